// Round 1
// baseline (390.173 us; speedup 1.0000x reference)
//
#include <hip/hip_runtime.h>
#include <cstdint>
#include <cstddef>

typedef _Float16 f16;
typedef _Float16 f16x8 __attribute__((ext_vector_type(8)));
typedef float f32x4 __attribute__((ext_vector_type(4)));

#define AS1 __attribute__((address_space(1)))
#define AS3 __attribute__((address_space(3)))

// async 16B global->LDS, per-lane source addr, LDS dst = wave-uniform base + lane*16
__device__ __forceinline__ void gl_lds16(const void* g, void* l) {
  __builtin_amdgcn_global_load_lds((AS1 void*)g, (AS3 void*)l, 16u, 0, 0u);
}

// c_tab[parity][a(tap)][i(conv-weight idx)] — folded FIR/upsample coefficients
__constant__ float c_tab[2][3][3] = {
  {{0.75f, 0.25f, 0.00f}, {0.25f, 0.75f, 0.75f}, {0.00f, 0.00f, 0.25f}},
  {{0.25f, 0.00f, 0.00f}, {0.75f, 0.75f, 0.25f}, {0.00f, 0.25f, 0.75f}}
};

// ---------------- Et build: Et[jj=oc*4+p][k=(ay*3+ax)*256+ic] (f16, [1024][2304]) ----
__global__ __launch_bounds__(256) void build_E_k(const float* __restrict__ W,
                                                 f16* __restrict__ Et) {
  const int oc = blockIdx.x;   // 256
  const int ic = threadIdx.x;  // 256
  float w[9];
  const float* wp = W + ((size_t)oc * 256 + ic) * 9;
#pragma unroll
  for (int t = 0; t < 9; ++t) w[t] = wp[t];
#pragma unroll
  for (int py = 0; py < 2; ++py)
#pragma unroll
    for (int px = 0; px < 2; ++px) {
      const int p = py * 2 + px;
#pragma unroll
      for (int ay = 0; ay < 3; ++ay)
#pragma unroll
        for (int ax = 0; ax < 3; ++ax) {
          float s = 0.f;
#pragma unroll
          for (int iy = 0; iy < 3; ++iy)
#pragma unroll
            for (int ix = 0; ix < 3; ++ix)
              s += w[iy * 3 + ix] * c_tab[py][ay][iy] * c_tab[px][ax][ix];
          Et[(size_t)(oc * 4 + p) * 2304 + (ay * 3 + ax) * 256 + ic] = (f16)s;
        }
    }
}

// ---------------- zero Ah (includes halo) : 8*66*66*256 f16 = 17,842,176 B ----------
__global__ __launch_bounds__(256) void zero_A_k(uint4* __restrict__ p) {
  p[(size_t)blockIdx.x * 256 + threadIdx.x] = make_uint4(0u, 0u, 0u, 0u);
}

// ---------------- fill Ah interior: NCHW f32 -> NHWC(+halo) f16 via LDS transpose ---
__global__ __launch_bounds__(256) void fill_A_k(const float* __restrict__ In,
                                                f16* __restrict__ Ah) {
  const int bid = blockIdx.x;      // 8 n * 64 y * 8 ic-chunks = 4096
  const int icc = bid & 7;
  const int y = (bid >> 3) & 63;
  const int n = bid >> 9;
  const int ic0 = icc * 32;
  __shared__ float tile[32][65];  // +1 pad: write-phase reads stride-65, no conflicts
  const int tid = threadIdx.x;
  const int xl = tid & 63, icl4 = tid >> 6;
  const float* src = In + (((size_t)(n * 256 + ic0)) * 64 + y) * 64;
#pragma unroll
  for (int i = 0; i < 8; ++i) {
    const int icl = i * 4 + icl4;
    tile[icl][xl] = src[(size_t)icl * 4096 + xl];
  }
  __syncthreads();
  const int icl = tid & 31, x8 = tid >> 5;
  f16* dst = Ah + ((size_t)(n * 66 + y + 1) * 66 + 1) * 256 + ic0;
#pragma unroll
  for (int i = 0; i < 8; ++i) {
    const int x = i * 8 + x8;
    dst[(size_t)x * 256 + icl] = (f16)tile[icl][x];
  }
}

// ---------------- main GEMM: M=32768 (n,y,x) x N=1024 (oc*4+p) x K=2304 (r*256+ic) --
#define BM 128
#define BN 128
#define BK 32
#define KSTEPS 72

__global__ __launch_bounds__(256) void gemm_k(const f16* __restrict__ Ah,
                                              const f16* __restrict__ Et,
                                              const float* __restrict__ bias,
                                              float* __restrict__ out) {
  __shared__ __align__(16) f16 lA[BM * BK];  // [m][k], 64B rows
  __shared__ __align__(16) f16 lB[BN * BK];  // [jj][k], 64B rows
  const int tid = threadIdx.x;
  const int wave = tid >> 6;
  const int lane = tid & 63;
  const int bid = blockIdx.x;     // 2048 = 256 mt * 8 nt; nt fastest -> per-XCD Et slice stays L2-hot
  const int nt = bid & 7;
  const int mt = bid >> 3;
  const int m0 = mt * BM;
  const int jj0 = nt * BN;
  const int n = m0 >> 12;
  const int y0 = (m0 >> 6) & 63;  // tile covers y0, y0+1 (x full 0..63)

  // --- staging source pointers (per lane) ---
  const int arow = wave * 32 + (lane >> 2);        // A-tile row (instr0); instr1 = +16
  const int y_r = y0 + (arow >> 6);
  const int x_r = arow & 63;
  const f16* pA = Ah + ((size_t)(n * 66 + y_r + 1) * 66 + (x_r + 1)) * 256 + (lane & 3) * 8;
  const f16* pB = Et + (size_t)(jj0 + wave * 32 + (lane >> 2)) * 2304 + (lane & 3) * 8;
  f16* dA0 = lA + (wave * 32) * BK;
  f16* dA1 = lA + (wave * 32 + 16) * BK;
  f16* dB0 = lB + (wave * 32) * BK;
  f16* dB1 = lB + (wave * 32 + 16) * BK;

  // --- compute-side per-thread constants ---
  const int wm = wave >> 1, wn = wave & 1;  // 2x2 wave grid, each 64x64
  const int lr = lane & 15;
  const int lk = (lane >> 4) * 8;
  int aoff[4], boff[4];
#pragma unroll
  for (int i = 0; i < 4; ++i) {
    aoff[i] = (wm * 64 + i * 16 + lr) * BK + lk;
    boff[i] = (wn * 64 + i * 16 + lr) * BK + lk;
  }

  const f32x4 vzero = {0.f, 0.f, 0.f, 0.f};
  f32x4 acc[4][4];
#pragma unroll
  for (int i = 0; i < 4; ++i)
#pragma unroll
    for (int j = 0; j < 4; ++j) acc[i][j] = vzero;

  for (int ks = 0; ks < KSTEPS; ++ks) {
    const int k0 = ks * BK;
    const int r = k0 >> 8;         // tap index 0..8 (uniform)
    const int ic0 = k0 & 255;
    const int ayt = r / 3, axt = r - ayt * 3;
    const int delta = ((ayt - 1) * 66 + (axt - 1)) * 256 + ic0;  // halo keeps it in-bounds

    __syncthreads();  // LDS reads of previous step done before overwrite
    gl_lds16(pA + delta, dA0);
    gl_lds16(pA + delta + 16 * 256, dA1);   // +16 tile rows = +16 x
    gl_lds16(pB + k0, dB0);
    gl_lds16(pB + k0 + 16 * 2304, dB1);     // +16 jj rows
    __syncthreads();  // compiler drains vmcnt before barrier

    f16x8 af[4], bf[4];
#pragma unroll
    for (int mi = 0; mi < 4; ++mi) af[mi] = *(const f16x8*)(lA + aoff[mi]);
#pragma unroll
    for (int ni = 0; ni < 4; ++ni) bf[ni] = *(const f16x8*)(lB + boff[ni]);
#pragma unroll
    for (int mi = 0; mi < 4; ++mi)
#pragma unroll
      for (int ni = 0; ni < 4; ++ni)
        acc[mi][ni] = __builtin_amdgcn_mfma_f32_16x16x32_f16(af[mi], bf[ni], acc[mi][ni], 0, 0, 0);
  }

  // --- epilogue: C layout col=lane&15 (jj), row=(lane>>4)*4+v (m) ---
  const int yw = y0 + wm;
#pragma unroll
  for (int ni = 0; ni < 4; ++ni) {
    const int jj = jj0 + wn * 64 + ni * 16 + lr;
    const int oc = jj >> 2;
    const int py = (jj >> 1) & 1, px = jj & 1;
    const float bv = bias[oc];
    const int oy = 2 * yw + py;
    float* orow = out + ((size_t)(n * 256 + oc) * 128 + oy) * 128;
#pragma unroll
    for (int mi = 0; mi < 4; ++mi) {
      const int xb = mi * 16 + ((lane >> 4) << 2);
#pragma unroll
      for (int v = 0; v < 4; ++v) {
        orow[2 * (xb + v) + px] = acc[mi][ni][v] + bv;
      }
    }
  }
}

// ---------------- fallback (ws too small): direct, slow, correct ---------------------
__global__ __launch_bounds__(256) void fallback_k(const float* __restrict__ In,
                                                  const float* __restrict__ W,
                                                  const float* __restrict__ bias,
                                                  float* __restrict__ out) {
  const size_t idx = (size_t)blockIdx.x * 256 + threadIdx.x;
  const int ox = (int)(idx & 127), oy = (int)((idx >> 7) & 127);
  const int oc = (int)((idx >> 14) & 255);
  const int n = (int)(idx >> 22);
  const int px = ox & 1, py = oy & 1;
  const int x = ox >> 1, y = oy >> 1;
  float cy[3][3], cx[3][3];
#pragma unroll
  for (int a = 0; a < 3; ++a)
#pragma unroll
    for (int i = 0; i < 3; ++i) {
      cy[a][i] = c_tab[py][a][i];
      cx[a][i] = c_tab[px][a][i];
    }
  float acc = 0.f;
  const float* wbase = W + (size_t)oc * 2304;
  for (int ic = 0; ic < 256; ++ic) {
    const float* ib = In + (((size_t)(n * 256 + ic)) * 64 + y) * 64 + x;
    float pin[3][3];
#pragma unroll
    for (int ay = 0; ay < 3; ++ay) {
      const int yy = y + ay - 1;
#pragma unroll
      for (int ax = 0; ax < 3; ++ax) {
        const int xx = x + ax - 1;
        pin[ay][ax] = (yy >= 0 && yy < 64 && xx >= 0 && xx < 64)
                          ? ib[(ay - 1) * 64 + (ax - 1)] : 0.f;
      }
    }
    const float* w = wbase + ic * 9;
    float U[3][3];
#pragma unroll
    for (int ay = 0; ay < 3; ++ay)
#pragma unroll
      for (int ix = 0; ix < 3; ++ix)
        U[ay][ix] = cx[0][ix] * pin[ay][0] + cx[1][ix] * pin[ay][1] + cx[2][ix] * pin[ay][2];
#pragma unroll
    for (int iy = 0; iy < 3; ++iy)
#pragma unroll
      for (int ix = 0; ix < 3; ++ix) {
        const float V = cy[0][iy] * U[0][ix] + cy[1][iy] * U[1][ix] + cy[2][iy] * U[2][ix];
        acc += w[iy * 3 + ix] * V;
      }
  }
  out[idx] = acc + bias[oc];
}

extern "C" void kernel_launch(void* const* d_in, const int* in_sizes, int n_in,
                              void* d_out, int out_size, void* d_ws, size_t ws_size,
                              hipStream_t stream) {
  const float* In = (const float*)d_in[0];    // [8][256][64][64]
  const float* W = (const float*)d_in[1];     // [256][256][3][3]
  const float* bias = (const float*)d_in[2];  // [256]
  float* out = (float*)d_out;                 // [8][256][128][128]

  const size_t E_BYTES = (size_t)1024 * 2304 * 2;       // 4,718,592
  const size_t A_BYTES = (size_t)8 * 66 * 66 * 256 * 2; // 17,842,176

  if (ws_size >= E_BYTES + A_BYTES) {
    f16* Et = (f16*)d_ws;
    f16* Ah = (f16*)((char*)d_ws + E_BYTES);
    build_E_k<<<256, 256, 0, stream>>>(W, Et);
    zero_A_k<<<4356, 256, 0, stream>>>((uint4*)Ah);   // 4356*256*16B = full Ah
    fill_A_k<<<4096, 256, 0, stream>>>(In, Ah);
    gemm_k<<<2048, 256, 0, stream>>>(Ah, Et, bias, out);
  } else {
    fallback_k<<<131072, 256, 0, stream>>>(In, W, bias, out);
  }
}

// Round 2
// 336.328 us; speedup vs baseline: 1.1601x; 1.1601x over previous
//
#include <hip/hip_runtime.h>
#include <cstdint>
#include <cstddef>

typedef _Float16 f16;
typedef _Float16 f16x8 __attribute__((ext_vector_type(8)));
typedef float f32x4 __attribute__((ext_vector_type(4)));

#define AS1 __attribute__((address_space(1)))
#define AS3 __attribute__((address_space(3)))

// async 16B global->LDS, per-lane source addr, LDS dst = wave-uniform base + lane*16
__device__ __forceinline__ void gl_lds16(const void* g, void* l) {
  __builtin_amdgcn_global_load_lds((AS1 void*)g, (AS3 void*)l, 16u, 0, 0u);
}

// c_tab[parity][a(tap)][i(conv-weight idx)] — folded FIR/upsample coefficients
__constant__ float c_tab[2][3][3] = {
  {{0.75f, 0.25f, 0.00f}, {0.25f, 0.75f, 0.75f}, {0.00f, 0.00f, 0.25f}},
  {{0.25f, 0.00f, 0.00f}, {0.75f, 0.75f, 0.25f}, {0.00f, 0.25f, 0.75f}}
};

// =====================================================================================
// Fused prep:
//  blocks [0,256):        build Et3[c8][ay3][ax3][jj1024][ic32] f16 from W (f32)
//  blocks [256,256+4224): fill Ah[n8][y66][x66][ic256] f16 (NCHW->NHWC + zeroed halo)
//    4224 = 8 n * 66 y' * 8 ic-chunks; halo rows/cols zeroed by the same block that
//    owns the row -> no inter-block write overlap (dispatch order is undefined).
// =====================================================================================
__global__ __launch_bounds__(256) void prep_k(const float* __restrict__ W,
                                              const float* __restrict__ In,
                                              f16* __restrict__ Et,
                                              f16* __restrict__ Ah) {
  const int b = blockIdx.x;
  const int tid = threadIdx.x;
  if (b < 256) {
    // ---- Et3 build ----
    const int oc = b;
    const int ic = tid;
    const int c = ic >> 5, icl = ic & 31;
    float w[9];
    const float* wp = W + ((size_t)oc * 256 + ic) * 9;
#pragma unroll
    for (int t = 0; t < 9; ++t) w[t] = wp[t];
#pragma unroll
    for (int py = 0; py < 2; ++py)
#pragma unroll
      for (int px = 0; px < 2; ++px) {
        const int jj = oc * 4 + py * 2 + px;
#pragma unroll
        for (int ay = 0; ay < 3; ++ay)
#pragma unroll
          for (int ax = 0; ax < 3; ++ax) {
            float s = 0.f;
#pragma unroll
            for (int iy = 0; iy < 3; ++iy)
#pragma unroll
              for (int ix = 0; ix < 3; ++ix)
                s += w[iy * 3 + ix] * c_tab[py][ay][iy] * c_tab[px][ax][ix];
            Et[((size_t)(((c * 3 + ay) * 3 + ax) * 1024 + jj)) * 32 + icl] = (f16)s;
          }
      }
  } else {
    // ---- Ah fill ----
    const int bid2 = b - 256;
    const int icc = bid2 & 7;
    const int v = bid2 >> 3;       // 0..527
    const int n = v / 66;
    const int yp = v - n * 66;     // y' in 0..65
    const int ic0 = icc * 32;
    const int icl = tid & 31, x8 = tid >> 5;
    f16* rowbase = Ah + ((size_t)(n * 66 + yp) * 66) * 256 + ic0;
    if (yp == 0 || yp == 65) {
      // full halo row -> zeros
#pragma unroll
      for (int i = 0; i < 9; ++i) {
        const int xp = i * 8 + x8;
        if (xp < 66) rowbase[(size_t)xp * 256 + icl] = (f16)0.f;
      }
    } else {
      const int y = yp - 1;
      __shared__ float tile[32][65];  // +1 pad: write-phase stride-65 reads, no conflicts
      const int xl = tid & 63, icl4 = tid >> 6;
      const float* src = In + (((size_t)(n * 256 + ic0)) * 64 + y) * 64;
#pragma unroll
      for (int i = 0; i < 8; ++i) {
        const int icl_ = i * 4 + icl4;
        tile[icl_][xl] = src[(size_t)icl_ * 4096 + xl];
      }
      __syncthreads();
      f16* dst = rowbase + 256;  // x'=1
#pragma unroll
      for (int i = 0; i < 8; ++i) {
        const int x = i * 8 + x8;
        dst[(size_t)x * 256 + icl] = (f16)tile[icl][x];
      }
      if (x8 == 0) {  // halo columns x'=0 and x'=65
        rowbase[icl] = (f16)0.f;
        rowbase[(size_t)65 * 256 + icl] = (f16)0.f;
      }
    }
  }
}

// =====================================================================================
// Implicit-GEMM conv: M=32768 (n,y,x) x N=1024 (jj=oc*4+p), K = 8 ic-chunks x 3 ay x
// (3 ax x 32 ic). Per stage (c,ay): A = 2 Ah rows x 66 x x 32 ic (8448 B, reused by
// all 3 ax taps), B = 3 contiguous Et3 ax-slabs (24576 B). 24 stages, 48 MFMA/stage.
// =====================================================================================
__global__ __launch_bounds__(256) void gemm_k(const f16* __restrict__ Ah,
                                              const f16* __restrict__ Et,
                                              const float* __restrict__ bias,
                                              float* __restrict__ out) {
  __shared__ __align__(16) f16 lA[4224];   // [r2][x66][ic32]  8448 B
  __shared__ __align__(16) f16 lB[12288];  // [ax3][jj128][ic32] 24576 B
  const int tid = threadIdx.x;
  const int wave = tid >> 6;
  const int lane = tid & 63;
  const int bid = blockIdx.x;  // 2048 = 256 mt * 8 nt; nt fastest -> Et slice per-XCD L2-hot
  const int nt = bid & 7;
  const int mt = bid >> 3;
  const int m0 = mt * 128;
  const int jj0 = nt * 128;
  const int n = m0 >> 12;
  const int y0 = (m0 >> 6) & 63;  // even, 0..62; tile covers y0,y0+1 (x full 0..63)

  // ---- staging per-lane constants (fixed across stages) ----
  // A: 8448 B = 8 full 1KB slots + 256 B tail. Slot s covers x-units u = s*16..s*16+15,
  //    u in 0..131 -> row = u>=66, x = u-66*row. Tail: u=128..131, lanes 0..15, wave 3.
  int goA[2];
#pragma unroll
  for (int i = 0; i < 2; ++i) {
    const int s = wave * 2 + i;
    const int u = s * 16 + (lane >> 2);
    const int row = (u >= 66) ? 1 : 0;
    const int x = u - 66 * row;
    goA[i] = ((row * 66 + x) * 256 + (lane & 3) * 8) * 2;  // bytes into Ah from stage base
  }
  const int goAt = ((66 + 62 + (lane >> 2)) * 256 + (lane & 3) * 8) * 2;  // row1,x62..65
  // B: 24 slots of 1KB; slot t: ax = t>>3, sub = t&7 (16 jj each). Wave w takes t=w+4j.
  int goB[6];
#pragma unroll
  for (int j = 0; j < 6; ++j) {
    const int t = wave + 4 * j;
    const int ax = t >> 3, sub = t & 7;
    goB[j] = (ax * 32768 + (sub * 16 + (lane >> 2)) * 32 + (lane & 3) * 8) * 2;
  }
  char* const lAb = (char*)lA;
  char* const lBb = (char*)lB;
  char* const dA0 = lAb + (wave * 2 + 0) * 1024;
  char* const dA1 = lAb + (wave * 2 + 1) * 1024;
  char* const dAt = lAb + 8192;

  // ---- compute-side constants ----
  const int wm = wave >> 1, wn = wave & 1;  // 2x2 wave grid, each 64(m) x 64(jj)
  const int lr = lane & 15;
  const int base_a = wm * 4224 + lr * 64 + (lane >> 4) * 16;           // + (mi*16+ax)*64
  const int base_b = (wn * 64 + lr) * 64 + (lane >> 4) * 16;           // + ax*8192 + ni*1024

  const char* const aN = (const char*)Ah + (size_t)(n * 66 + y0) * 33792;  // 66*256*2 per y
  const char* const bE = (const char*)Et + (size_t)jj0 * 64;               // jj0*32*2

  const f32x4 vzero = {0.f, 0.f, 0.f, 0.f};
  f32x4 acc[4][4];
#pragma unroll
  for (int i = 0; i < 4; ++i)
#pragma unroll
    for (int j = 0; j < 4; ++j) acc[i][j] = vzero;

#pragma unroll 1
  for (int c = 0; c < 8; ++c) {
#pragma unroll 1
    for (int ay = 0; ay < 3; ++ay) {
      const char* aP = aN + ay * 33792 + c * 64;
      const char* bP = bE + (size_t)(c * 3 + ay) * 196608;  // 98304 f16 per (c,ay)

      __syncthreads();  // previous stage's LDS reads done before overwrite
      gl_lds16(aP + goA[0], dA0);
      gl_lds16(aP + goA[1], dA1);
      if (wave == 3 && lane < 16) gl_lds16(aP + goAt, dAt);
#pragma unroll
      for (int j = 0; j < 6; ++j) gl_lds16(bP + goB[j], lBb + (wave + 4 * j) * 1024);
      __syncthreads();  // drains vmcnt before barrier

#pragma unroll
      for (int ax = 0; ax < 3; ++ax) {
        f16x8 af[4], bf[4];
#pragma unroll
        for (int mi = 0; mi < 4; ++mi)
          af[mi] = *(const f16x8*)(lAb + base_a + (mi * 16 + ax) * 64);
#pragma unroll
        for (int ni = 0; ni < 4; ++ni)
          bf[ni] = *(const f16x8*)(lBb + base_b + ax * 8192 + ni * 1024);
#pragma unroll
        for (int mi = 0; mi < 4; ++mi)
#pragma unroll
          for (int ni = 0; ni < 4; ++ni)
            acc[mi][ni] =
                __builtin_amdgcn_mfma_f32_16x16x32_f16(af[mi], bf[ni], acc[mi][ni], 0, 0, 0);
      }
    }
  }

  // ---- epilogue: C layout col=lane&15 (jj), row=(lane>>4)*4+v (m) ----
  const int yw = y0 + wm;
#pragma unroll
  for (int ni = 0; ni < 4; ++ni) {
    const int jj = jj0 + wn * 64 + ni * 16 + lr;
    const int oc = jj >> 2;
    const int py = (jj >> 1) & 1, px = jj & 1;
    const float bv = bias[oc];
    const int oy = 2 * yw + py;
    float* orow = out + ((size_t)(n * 256 + oc) * 128 + oy) * 128;
#pragma unroll
    for (int mi = 0; mi < 4; ++mi) {
      const int xb = mi * 16 + ((lane >> 4) << 2);
#pragma unroll
      for (int v = 0; v < 4; ++v) {
        orow[2 * (xb + v) + px] = acc[mi][ni][v] + bv;
      }
    }
  }
}

// ---------------- fallback (ws too small): direct, slow, correct ---------------------
__global__ __launch_bounds__(256) void fallback_k(const float* __restrict__ In,
                                                  const float* __restrict__ W,
                                                  const float* __restrict__ bias,
                                                  float* __restrict__ out) {
  const size_t idx = (size_t)blockIdx.x * 256 + threadIdx.x;
  const int ox = (int)(idx & 127), oy = (int)((idx >> 7) & 127);
  const int oc = (int)((idx >> 14) & 255);
  const int n = (int)(idx >> 22);
  const int px = ox & 1, py = oy & 1;
  const int x = ox >> 1, y = oy >> 1;
  float cy[3][3], cx[3][3];
#pragma unroll
  for (int a = 0; a < 3; ++a)
#pragma unroll
    for (int i = 0; i < 3; ++i) {
      cy[a][i] = c_tab[py][a][i];
      cx[a][i] = c_tab[px][a][i];
    }
  float acc = 0.f;
  const float* wbase = W + (size_t)oc * 2304;
  for (int ic = 0; ic < 256; ++ic) {
    const float* ib = In + (((size_t)(n * 256 + ic)) * 64 + y) * 64 + x;
    float pin[3][3];
#pragma unroll
    for (int ay = 0; ay < 3; ++ay) {
      const int yy = y + ay - 1;
#pragma unroll
      for (int ax = 0; ax < 3; ++ax) {
        const int xx = x + ax - 1;
        pin[ay][ax] = (yy >= 0 && yy < 64 && xx >= 0 && xx < 64)
                          ? ib[(ay - 1) * 64 + (ax - 1)] : 0.f;
      }
    }
    const float* w = wbase + ic * 9;
    float U[3][3];
#pragma unroll
    for (int ay = 0; ay < 3; ++ay)
#pragma unroll
      for (int ix = 0; ix < 3; ++ix)
        U[ay][ix] = cx[0][ix] * pin[ay][0] + cx[1][ix] * pin[ay][1] + cx[2][ix] * pin[ay][2];
#pragma unroll
    for (int iy = 0; iy < 3; ++iy)
#pragma unroll
      for (int ix = 0; ix < 3; ++ix) {
        const float V = cy[0][iy] * U[0][ix] + cy[1][iy] * U[1][ix] + cy[2][iy] * U[2][ix];
        acc += w[iy * 3 + ix] * V;
      }
  }
  out[idx] = acc + bias[oc];
}

extern "C" void kernel_launch(void* const* d_in, const int* in_sizes, int n_in,
                              void* d_out, int out_size, void* d_ws, size_t ws_size,
                              hipStream_t stream) {
  const float* In = (const float*)d_in[0];    // [8][256][64][64]
  const float* W = (const float*)d_in[1];     // [256][256][3][3]
  const float* bias = (const float*)d_in[2];  // [256]
  float* out = (float*)d_out;                 // [8][256][128][128]

  const size_t E_BYTES = (size_t)1024 * 2304 * 2;       // 4,718,592
  const size_t A_BYTES = (size_t)8 * 66 * 66 * 256 * 2; // 17,842,176

  if (ws_size >= E_BYTES + A_BYTES) {
    f16* Et = (f16*)d_ws;
    f16* Ah = (f16*)((char*)d_ws + E_BYTES);
    prep_k<<<256 + 4224, 256, 0, stream>>>(W, In, Et, Ah);
    gemm_k<<<2048, 256, 0, stream>>>(Ah, Et, bias, out);
  } else {
    fallback_k<<<131072, 256, 0, stream>>>(In, W, bias, out);
  }
}